// Round 4
// baseline (736.708 us; speedup 1.0000x reference)
//
#include <hip/hip_runtime.h>
#include <hip/hip_bf16.h>

#define N_NODES 100000
#define N_EDGES 1600000
#define IN_DIM 128
#define OUT_DIM 64
#define EDGE_DIM 32
#define NH 4
#define HD 16
#define NEG_SLOPE 0.2f

#define W_SRC_ELEMS (OUT_DIM * IN_DIM)   // 8192
#define W_EDGE_ELEMS (OUT_DIM * EDGE_DIM) // 2048
#define W_TOTAL (2 * W_SRC_ELEMS + W_EDGE_ELEMS) // 18432

typedef __attribute__((ext_vector_type(8))) short short8;
typedef __attribute__((ext_vector_type(4))) float floatx4;

// Split an fp32 octet into bf16 hi/lo fragments: x = hi + lo + O(eps^2 * x).
__device__ __forceinline__ void cvt_hilo(const float* __restrict__ p, short8& hi, short8& lo)
{
    floatx4 x0 = *(const floatx4*)p;
    floatx4 x1 = *(const floatx4*)(p + 4);
    float v[8] = {x0[0], x0[1], x0[2], x0[3], x1[0], x1[1], x1[2], x1[3]};
#pragma unroll
    for (int j = 0; j < 8; ++j) {
        union { __hip_bfloat16 b; short s; } h, l;
        h.b = __float2bfloat16(v[j]);
        l.b = __float2bfloat16(v[j] - __bfloat162float(h.b));
        hi[j] = h.s;
        lo[j] = l.s;
    }
}

// Same, but streaming (nontemporal) source load — evict-first, keeps L3 for
// the gather tables.
__device__ __forceinline__ void cvt_hilo_nt(const float* __restrict__ p, short8& hi, short8& lo)
{
    floatx4 x0 = __builtin_nontemporal_load((const floatx4*)p);
    floatx4 x1 = __builtin_nontemporal_load((const floatx4*)(p + 4));
    float v[8] = {x0[0], x0[1], x0[2], x0[3], x1[0], x1[1], x1[2], x1[3]};
#pragma unroll
    for (int j = 0; j < 8; ++j) {
        union { __hip_bfloat16 b; short s; } h, l;
        h.b = __float2bfloat16(v[j]);
        l.b = __float2bfloat16(v[j] - __bfloat162float(h.b));
        hi[j] = h.s;
        lo[j] = l.s;
    }
}

// ---------------------------------------------------------------------------
// Kernel W: precompute hi/lo bf16 split of W_src|W_dst|W_edge (one pass).
// ---------------------------------------------------------------------------
__global__ __launch_bounds__(256) void wsplit_kernel(
    const float* __restrict__ W_src,
    const float* __restrict__ W_dst,
    const float* __restrict__ W_edge,
    short* __restrict__ w_hi,
    short* __restrict__ w_lo)
{
    int g = blockIdx.x * 256 + threadIdx.x;
    if (g >= W_TOTAL) return;
    float v;
    if (g < W_SRC_ELEMS)            v = W_src[g];
    else if (g < 2 * W_SRC_ELEMS)   v = W_dst[g - W_SRC_ELEMS];
    else                            v = W_edge[g - 2 * W_SRC_ELEMS];
    union { __hip_bfloat16 b; short s; } h, l;
    h.b = __float2bfloat16(v);
    l.b = __float2bfloat16(v - __bfloat162float(h.b));
    w_hi[g] = h.s;
    w_lo[g] = l.s;
}

// ---------------------------------------------------------------------------
// Kernel A: feat_src = node_feat @ W_src^T, feat_dst = node_feat @ W_dst^T
// node_feat read is streaming (nt); fs/fd writes stay cached (consumed by
// the gather kernels next).
// ---------------------------------------------------------------------------
__global__ __launch_bounds__(64) void node_proj_kernel(
    const float* __restrict__ node_feat,
    const short* __restrict__ w_hi,
    const short* __restrict__ w_lo,
    float* __restrict__ feat_src,
    float* __restrict__ feat_dst)
{
    const int lane = threadIdx.x;
    const int col  = lane & 15;
    const int quad = lane >> 4;
    const int m0   = blockIdx.x * 16;

    floatx4 acc[8];
#pragma unroll
    for (int t = 0; t < 8; ++t) acc[t] = (floatx4){0.f, 0.f, 0.f, 0.f};

#pragma unroll
    for (int kc = 0; kc < 4; ++kc) {
        short8 ahi, alo;
        cvt_hilo_nt(node_feat + (size_t)(m0 + col) * IN_DIM + kc * 32 + quad * 8, ahi, alo);
#pragma unroll
        for (int t = 0; t < 8; ++t) {
            int o = (t < 4 ? 0 : OUT_DIM) + (t & 3) * 16 + col;
            size_t off = (size_t)o * IN_DIM + kc * 32 + quad * 8;
            short8 bhi = *(const short8*)(w_hi + off);
            short8 blo = *(const short8*)(w_lo + off);
            acc[t] = __builtin_amdgcn_mfma_f32_16x16x32_bf16(ahi, bhi, acc[t], 0, 0, 0);
            acc[t] = __builtin_amdgcn_mfma_f32_16x16x32_bf16(ahi, blo, acc[t], 0, 0, 0);
            acc[t] = __builtin_amdgcn_mfma_f32_16x16x32_bf16(alo, bhi, acc[t], 0, 0, 0);
        }
    }

#pragma unroll
    for (int t = 0; t < 8; ++t) {
        float* out = (t < 4) ? feat_src : feat_dst;
        int ob = (t & 3) * 16;
#pragma unroll
        for (int r = 0; r < 4; ++r) {
            int node = m0 + quad * 4 + r;
            out[(size_t)node * OUT_DIM + ob + col] = acc[t][r];
        }
    }
}

// ---------------------------------------------------------------------------
// Kernel B: edge logits + exp, 2 tiles (32 edges) per wave, butterfly reduce.
// Streaming data (edge_feat, src, dst, ex_out) is nontemporal; the fs/fd
// gathers and W frags stay cached so the 51 MB feat tables live in L3.
// ---------------------------------------------------------------------------
__global__ __launch_bounds__(256) void edge_logits_kernel(
    const float* __restrict__ edge_feat,
    const short* __restrict__ we_hi,   // W_edge hi, [64][32]
    const short* __restrict__ we_lo,
    const float* __restrict__ attn,
    const int* __restrict__ src,
    const int* __restrict__ dst,
    const float* __restrict__ feat_src,
    const float* __restrict__ feat_dst,
    float* __restrict__ ex_out,
    int* __restrict__ deg)
{
    const int lane = threadIdx.x & 63;
    const int wave = threadIdx.x >> 6;
    const int col  = lane & 15;
    const int quad = lane >> 4;
    const size_t ebase0 = ((size_t)blockIdx.x * 4 + wave) * 32;   // 2 tiles x 16

    // phase 1: issue all src/dst loads (streaming)
    int s[2][4], d[2][4];
#pragma unroll
    for (int u = 0; u < 2; ++u)
#pragma unroll
        for (int r = 0; r < 4; ++r) {
            s[u][r] = __builtin_nontemporal_load(&src[ebase0 + u * 16 + quad * 4 + r]);
            d[u][r] = __builtin_nontemporal_load(&dst[ebase0 + u * 16 + quad * 4 + r]);
        }

    // phase 2: edge_feat for both tiles (streaming)
    short8 ahi[2], alo[2];
#pragma unroll
    for (int u = 0; u < 2; ++u)
        cvt_hilo_nt(edge_feat + (ebase0 + u * 16 + col) * EDGE_DIM + quad * 8, ahi[u], alo[u]);

    float att[4];
#pragma unroll
    for (int t = 0; t < 4; ++t) att[t] = attn[t * 16 + col];

    // phase 3: MFMAs, W-frags loaded once and shared between the two tiles
    floatx4 acc[2][4];
#pragma unroll
    for (int t = 0; t < 4; ++t) {
        size_t off = (size_t)(t * 16 + col) * EDGE_DIM + quad * 8;
        short8 bhi = *(const short8*)(we_hi + off);
        short8 blo = *(const short8*)(we_lo + off);
#pragma unroll
        for (int u = 0; u < 2; ++u) {
            floatx4 c = (floatx4){0.f, 0.f, 0.f, 0.f};
            c = __builtin_amdgcn_mfma_f32_16x16x32_bf16(ahi[u], bhi, c, 0, 0, 0);
            c = __builtin_amdgcn_mfma_f32_16x16x32_bf16(ahi[u], blo, c, 0, 0, 0);
            c = __builtin_amdgcn_mfma_f32_16x16x32_bf16(alo[u], bhi, c, 0, 0, 0);
            acc[u][t] = c;
        }
    }

    const int j = col;
    const int rsel = j >> 2;

#pragma unroll
    for (int u = 0; u < 2; ++u) {
        // per-lane partial contributions p[r*4+t]; fs/fd gathers CACHED
        float p[16];
#pragma unroll
        for (int r = 0; r < 4; ++r)
#pragma unroll
            for (int t = 0; t < 4; ++t) {
                float v = acc[u][t][r]
                        + feat_src[(size_t)s[u][r] * OUT_DIM + t * 16 + col]
                        + feat_dst[(size_t)d[u][r] * OUT_DIM + t * 16 + col];
                v = (v > 0.f) ? v : NEG_SLOPE * v;
                p[r * 4 + t] = v * att[t];
            }

        // butterfly tree: combo j's sum lands in lane j
        {
            const bool u8 = (col & 8) != 0;
#pragma unroll
            for (int i = 0; i < 8; ++i) {
                float keep = u8 ? p[i + 8] : p[i];
                float send = u8 ? p[i] : p[i + 8];
                p[i] = keep + __shfl_xor(send, 8);
            }
            const bool u4 = (col & 4) != 0;
#pragma unroll
            for (int i = 0; i < 4; ++i) {
                float keep = u4 ? p[i + 4] : p[i];
                float send = u4 ? p[i] : p[i + 4];
                p[i] = keep + __shfl_xor(send, 4);
            }
            const bool u2 = (col & 2) != 0;
#pragma unroll
            for (int i = 0; i < 2; ++i) {
                float keep = u2 ? p[i + 2] : p[i];
                float send = u2 ? p[i] : p[i + 2];
                p[i] = keep + __shfl_xor(send, 2);
            }
            const bool u1 = (col & 1) != 0;
            {
                float keep = u1 ? p[1] : p[0];
                float send = u1 ? p[0] : p[1];
                p[0] = keep + __shfl_xor(send, 1);
            }
        }

        float ev = __expf(p[0]);
        __builtin_nontemporal_store(ev, &ex_out[(ebase0 + u * 16) * NH + lane]);

        int dd = d[u][0];
#pragma unroll
        for (int r = 1; r < 4; ++r) dd = (rsel == r) ? d[u][r] : dd;
        if ((j & 3) == 0) atomicAdd(&deg[dd], 1);
    }
}

// ---------------------------------------------------------------------------
// Hierarchical scan of deg[N] -> row_ptr[N+1] (exclusive), cursor[N].
// ---------------------------------------------------------------------------
#define SCAN_BLOCKS 98

__global__ __launch_bounds__(256) void scan_phase1(
    const int* __restrict__ deg, int* __restrict__ partial)
{
    __shared__ int red[256];
    const int tid = threadIdx.x;
    const int base = blockIdx.x * 1024 + tid * 4;
    int s = 0;
#pragma unroll
    for (int i = 0; i < 4; ++i) {
        int idx = base + i;
        if (idx < N_NODES) s += deg[idx];
    }
    red[tid] = s;
    __syncthreads();
    for (int off = 128; off > 0; off >>= 1) {
        if (tid < off) red[tid] += red[tid + off];
        __syncthreads();
    }
    if (tid == 0) partial[blockIdx.x] = red[0];
}

__global__ __launch_bounds__(128) void scan_phase2(
    const int* __restrict__ partial, int* __restrict__ block_off, int* __restrict__ row_ptr)
{
    __shared__ int buf[128];
    const int tid = threadIdx.x;
    buf[tid] = (tid < SCAN_BLOCKS) ? partial[tid] : 0;
    __syncthreads();
    for (int off = 1; off < 128; off <<= 1) {
        int v = buf[tid];
        int add = (tid >= off) ? buf[tid - off] : 0;
        __syncthreads();
        buf[tid] = v + add;
        __syncthreads();
    }
    if (tid < SCAN_BLOCKS) block_off[tid] = (tid > 0) ? buf[tid - 1] : 0;
    if (tid == 0) row_ptr[N_NODES] = N_EDGES;
}

__global__ __launch_bounds__(256) void scan_phase3(
    const int* __restrict__ deg, const int* __restrict__ block_off,
    int* __restrict__ row_ptr, int* __restrict__ cursor)
{
    __shared__ int tsum[256];
    const int tid = threadIdx.x;
    const int base = blockIdx.x * 1024 + tid * 4;
    int d[4];
    int s = 0;
#pragma unroll
    for (int i = 0; i < 4; ++i) {
        int idx = base + i;
        d[i] = (idx < N_NODES) ? deg[idx] : 0;
        s += d[i];
    }
    tsum[tid] = s;
    __syncthreads();
    for (int off = 1; off < 256; off <<= 1) {
        int v = tsum[tid];
        int add = (tid >= off) ? tsum[tid - off] : 0;
        __syncthreads();
        tsum[tid] = v + add;
        __syncthreads();
    }
    int prefix = block_off[blockIdx.x] + ((tid > 0) ? tsum[tid - 1] : 0);
#pragma unroll
    for (int i = 0; i < 4; ++i) {
        int idx = base + i;
        if (idx < N_NODES) {
            row_ptr[idx] = prefix;
            cursor[idx]  = prefix;
            prefix += d[i];
        }
    }
}

// ---------------------------------------------------------------------------
// Kernel F: bucket-fill in CONSUMPTION ORDER; all traffic is stream-once,
// so everything is nontemporal.
// ---------------------------------------------------------------------------
__global__ __launch_bounds__(256) void bucket_fill_kernel(
    const int* __restrict__ dst,
    const int* __restrict__ src,
    const float* __restrict__ ex,      // [E][4], original edge order
    int* __restrict__ cursor,
    int* __restrict__ esrc,            // [E]
    float* __restrict__ exb)           // [E][4], bucket order
{
    int e = blockIdx.x * 256 + threadIdx.x;
    int pos = atomicAdd(&cursor[__builtin_nontemporal_load(&dst[e])], 1);
    __builtin_nontemporal_store(__builtin_nontemporal_load(&src[e]), &esrc[pos]);
    floatx4 v = __builtin_nontemporal_load((const floatx4*)ex + e);
    __builtin_nontemporal_store(v, (floatx4*)exb + pos);
}

// ---------------------------------------------------------------------------
// Kernel G: gather-side aggregation, 8-wide pipelined inner loop.
// esrc/exb streams and the out write are nontemporal; feat_src gathers
// stay cached (25.6 MB table, L3-resident).
// ---------------------------------------------------------------------------
__global__ __launch_bounds__(256) void aggregate_kernel(
    const int* __restrict__ row_ptr,
    const int* __restrict__ esrc,
    const float* __restrict__ exb,
    const float* __restrict__ feat_src,
    const float* __restrict__ bias,
    float* __restrict__ seg_sum,
    float* __restrict__ out)
{
    const int node = blockIdx.x * 4 + (threadIdx.x >> 6);
    if (node >= N_NODES) return;
    const int lane = threadIdx.x & 63;
    const int h = lane >> 4;

    const int start = row_ptr[node];
    const int end   = row_ptr[node + 1];

    float acc = 0.f;
    float ssum = 0.f;

    int j = start;
    for (; j + 8 <= end; j += 8) {
        int   s_[8];
        float e_[8];
        float f_[8];
#pragma unroll
        for (int i = 0; i < 8; ++i) s_[i] = __builtin_nontemporal_load(&esrc[j + i]);
#pragma unroll
        for (int i = 0; i < 8; ++i) e_[i] = __builtin_nontemporal_load(&exb[(size_t)(j + i) * NH + h]);
#pragma unroll
        for (int i = 0; i < 8; ++i) f_[i] = feat_src[(size_t)s_[i] * OUT_DIM + lane];
#pragma unroll
        for (int i = 0; i < 8; ++i) {
            acc = fmaf(f_[i], e_[i], acc);
            ssum += e_[i];
        }
    }
    for (; j + 4 <= end; j += 4) {
        int   s_[4];
        float e_[4];
        float f_[4];
#pragma unroll
        for (int i = 0; i < 4; ++i) s_[i] = __builtin_nontemporal_load(&esrc[j + i]);
#pragma unroll
        for (int i = 0; i < 4; ++i) e_[i] = __builtin_nontemporal_load(&exb[(size_t)(j + i) * NH + h]);
#pragma unroll
        for (int i = 0; i < 4; ++i) f_[i] = feat_src[(size_t)s_[i] * OUT_DIM + lane];
#pragma unroll
        for (int i = 0; i < 4; ++i) {
            acc = fmaf(f_[i], e_[i], acc);
            ssum += e_[i];
        }
    }
    for (; j < end; ++j) {
        int s = __builtin_nontemporal_load(&esrc[j]);
        float ev = __builtin_nontemporal_load(&exb[(size_t)j * NH + h]);
        acc = fmaf(feat_src[(size_t)s * OUT_DIM + lane], ev, acc);
        ssum += ev;
    }

    if ((lane & 15) == 0) seg_sum[(size_t)node * NH + h] = ssum;
    float inv = (ssum > 0.f) ? 1.f / ssum : 0.f;
    __builtin_nontemporal_store(fmaf(acc, inv, bias[lane]), &out[(size_t)node * OUT_DIM + lane]);
}

// ---------------------------------------------------------------------------
// Kernel C: alpha = ex / seg_sum[dst]  (one thread per edge, float4).
// alpha/dst are streams (nt); seg_sum gather stays cached (400 KB table).
// ---------------------------------------------------------------------------
__global__ __launch_bounds__(256) void normalize_kernel(
    const float* __restrict__ seg_sum,
    const int* __restrict__ dst,
    float* __restrict__ alpha)
{
    int e = blockIdx.x * 256 + threadIdx.x;   // e < E
    int d = __builtin_nontemporal_load(&dst[e]);
    floatx4 ex4 = __builtin_nontemporal_load((const floatx4*)alpha + e);
    floatx4 ss  = *((const floatx4*)seg_sum + d);
    floatx4 r;
    r[0] = ex4[0] / ss[0];
    r[1] = ex4[1] / ss[1];
    r[2] = ex4[2] / ss[2];
    r[3] = ex4[3] / ss[3];
    __builtin_nontemporal_store(r, (floatx4*)alpha + e);
}

// ---------------------------------------------------------------------------
extern "C" void kernel_launch(void* const* d_in, const int* in_sizes, int n_in,
                              void* d_out, int out_size, void* d_ws, size_t ws_size,
                              hipStream_t stream)
{
    const float* node_feat = (const float*)d_in[0];
    const float* edge_feat = (const float*)d_in[1];
    const float* W_src     = (const float*)d_in[2];
    const float* W_dst     = (const float*)d_in[3];
    const float* W_edge    = (const float*)d_in[4];
    const float* attn      = (const float*)d_in[5];
    const float* bias      = (const float*)d_in[6];
    const int* src = (const int*)d_in[7];
    const int* dst = (const int*)d_in[8];

    // workspace layout (exb aliases feat_dst, dead after edge_logits)
    float* ws       = (float*)d_ws;
    float* feat_src = ws;                                        // N*64 floats
    float* feat_dst = feat_src + (size_t)N_NODES * OUT_DIM;      // N*64 floats (== E*NH!)
    float* exb      = feat_dst;                                  // reuse after edge_logits
    float* seg_sum  = feat_dst + (size_t)N_NODES * OUT_DIM;      // N*4 floats
    int*   deg      = (int*)(seg_sum + (size_t)N_NODES * NH);    // N ints
    int*   row_ptr  = deg + N_NODES;                             // N+1
    int*   cursor   = row_ptr + N_NODES + 1;                     // N
    int*   esrc     = cursor + N_NODES;                          // E ints
    int*   partial  = esrc + N_EDGES;                            // 98
    int*   boff     = partial + 128;                             // 98
    short* w_hi     = (short*)(boff + 128);                      // 18432 shorts
    short* w_lo     = w_hi + W_TOTAL;

    float* rst_out   = (float*)d_out;
    float* alpha_out = rst_out + (size_t)N_NODES * OUT_DIM;   // holds ex, then alpha

    hipMemsetAsync(deg, 0, (size_t)N_NODES * sizeof(int), stream);

    wsplit_kernel<<<(W_TOTAL + 255) / 256, 256, 0, stream>>>(W_src, W_dst, W_edge, w_hi, w_lo);
    node_proj_kernel<<<N_NODES / 16, 64, 0, stream>>>(node_feat, w_hi, w_lo, feat_src, feat_dst);
    edge_logits_kernel<<<N_EDGES / 128, 256, 0, stream>>>(edge_feat,
                                                          w_hi + 2 * W_SRC_ELEMS, w_lo + 2 * W_SRC_ELEMS,
                                                          attn, src, dst,
                                                          feat_src, feat_dst, alpha_out, deg);
    scan_phase1<<<SCAN_BLOCKS, 256, 0, stream>>>(deg, partial);
    scan_phase2<<<1, 128, 0, stream>>>(partial, boff, row_ptr);
    scan_phase3<<<SCAN_BLOCKS, 256, 0, stream>>>(deg, boff, row_ptr, cursor);
    bucket_fill_kernel<<<N_EDGES / 256, 256, 0, stream>>>(dst, src, alpha_out, cursor, esrc, exb);
    aggregate_kernel<<<(N_NODES + 3) / 4, 256, 0, stream>>>(row_ptr, esrc, exb,
                                                            feat_src, bias, seg_sum, rst_out);
    normalize_kernel<<<N_EDGES / 256, 256, 0, stream>>>(seg_sum, dst, alpha_out);
}